// Round 14
// baseline (1123.958 us; speedup 1.0000x reference)
//
#include <hip/hip_runtime.h>

typedef unsigned short u16;
typedef unsigned int   u32;

static __device__ __forceinline__ float sigf (float x){ return 1.0f/(1.0f+__expf(-x)); }
static __device__ __forceinline__ float tanh_(float x){ return 2.0f/(1.0f+__expf(-2.0f*x)) - 1.0f; }

// sizes
#define NM 2730            // 273*10 distinct (t, j=b%10) rows
#define N_O0 878080        // 245*128*28
#define N_O3 978432        // 273*128*28

static __device__ __forceinline__ int dot4(u32 a, u32 b, int acc){
#if __has_builtin(__builtin_amdgcn_sdot4)
  return __builtin_amdgcn_sdot4((int)a, (int)b, acc, false);
#else
  int s = acc;
  #pragma unroll
  for(int i=0;i<4;i++){
    int av = (int)((signed char)((a >> (8*i)) & 0xffu));
    int bv = (int)((signed char)((b >> (8*i)) & 0xffu));
    s += av*bv;
  }
  return s;
#endif
}

// ---- fused prep: xT + 6 transposes + Whh row scales ----
__global__ __launch_bounds__(256) void k_prep(
    const float* __restrict__ x,     float* __restrict__ xT,
    const float* __restrict__ wi0,   float* __restrict__ wT0,
    const float* __restrict__ wi1,   float* __restrict__ wT1,
    const float* __restrict__ wi2,   float* __restrict__ wT2,
    const float* __restrict__ wi3,   float* __restrict__ wT3,
    const float* __restrict__ lw,    float* __restrict__ lwT,
    const float* __restrict__ sw,    float* __restrict__ swT,
    const float* __restrict__ h0, const float* __restrict__ h1,
    const float* __restrict__ h2, const float* __restrict__ h3,
    float* __restrict__ zsc){
  int i = blockIdx.x*256 + threadIdx.x;
  if(i < 38400){                    // xT
    int t = i >> 7, b = i & 127;
    xT[i] = x[b*300 + t];
    return;
  }
  i -= 38400;
  if(i < 50176){ int c=i/1024, r=i-c*1024; wT0[i] = wi0[r*49 + c];  return; }
  i -= 50176;
  if(i < 262144){ int c=i>>10, r=i&1023; wT1[i] = wi1[r*256 + c];   return; }
  i -= 262144;
  if(i < 262144){ int c=i>>10, r=i&1023; wT2[i] = wi2[r*256 + c];   return; }
  i -= 262144;
  if(i < 262144){ int c=i>>10, r=i&1023; wT3[i] = wi3[r*256 + c];   return; }
  i -= 262144;
  if(i < 65536){ int c=i>>8, r=i&255; lwT[i] = lw[r*256 + c];       return; }
  i -= 65536;
  if(i < 7168){ int c=i/28, r=i-c*28; swT[i] = sw[r*256 + c];       return; }
  i -= 7168;
  if(i < 4096){                     // per-row absmax scale (int8)
    int l = i >> 10, r = i & 1023;
    const float* W = (l==0)?h0:(l==1)?h1:(l==2)?h2:h3;
    const float4* p = (const float4*)(W + (size_t)r*256);
    float m = 0.f;
    #pragma unroll 8
    for(int q=0;q<64;q++){
      float4 v = p[q];
      m = fmaxf(m, fmaxf(fmaxf(fabsf(v.x),fabsf(v.y)), fmaxf(fabsf(v.z),fabsf(v.w))));
    }
    zsc[i] = fmaxf(m, 1e-20f) * (1.0f/16129.0f);   // rowmax/(127*127)
  }
}

// ---- fused int8 pack + ES scan (scanB layout) ----
// per-layer u32 idx i: dw=i&3, u4=i>>2; tid=u4&1023, combo=u4>>10 (0..15);
// kg=tid&127, js=tid>>7 (0..7); q=combo>>3, rr=combo&7;
// row=rr*128+kg ; k0=js*32+q*16+dw*4
__global__ __launch_bounds__(256) void k_packes(
    const float* __restrict__ h0, const float* __restrict__ h1,
    const float* __restrict__ h2, const float* __restrict__ h3,
    const float* __restrict__ zsc, u32* __restrict__ W8,
    const float* __restrict__ xT, const float* __restrict__ alpha,
    const float* __restrict__ gamma, const float* __restrict__ iseas,
    float* __restrict__ ST, float* __restrict__ lvlT){
  if(blockIdx.x < 1024){
    int i = blockIdx.x*256 + threadIdx.x;      // 0..262143
    int l = i >> 16;
    int w = i & 65535;
    int dw = w & 3;
    int u4 = w >> 2;
    int tid = u4 & 1023;
    int combo = u4 >> 10;
    int kg = tid & 127, js = tid >> 7;
    int q = combo >> 3, rr = combo & 7;
    int row = rr*128 + kg;
    int k0  = js*32 + q*16 + dw*4;
    const float* W = (l==0)?h0:(l==1)?h1:(l==2)?h2:h3;
    float inv = 1.0f / (zsc[l*1024 + row] * 127.0f);
    u32 out = 0;
    #pragma unroll
    for(int b=0;b<4;b++){
      float v = W[(size_t)row*256 + k0 + b];
      int q8 = max(-127, min(127, __float2int_rn(v * inv)));
      out |= ((u32)(q8 & 0xff)) << (8*b);
    }
    W8[i] = out;
    return;
  }
  // ES scan (block 1024, threads 0..127)
  int b = threadIdx.x;
  if(b >= 128) return;
  float a = sigf(alpha[b]);
  float g = sigf(gamma[b]);
  float S0[7];
  #pragma unroll
  for(int i=0;i<7;i++){ S0[i] = __expf(iseas[b*7+i]); ST[i*128+b] = S0[i]; }
  ST[7*128+b] = S0[0];
  float q0=S0[1],q1=S0[2],q2=S0[3],q3=S0[4],q4=S0[5],q5=S0[6],q6=S0[0];
  float lvl = xT[b]/S0[0];
  lvlT[b] = lvl;
  for(int t=1;t<300;t++){
    float xt = xT[t*128+b];
    float s  = q0;
    lvl = a*(xt/s) + (1.0f-a)*lvl;
    float sn = g*(xt/lvl) + (1.0f-g)*s;
    q0=q1;q1=q2;q2=q3;q3=q4;q4=q5;q5=q6;q6=sn;
    lvlT[t*128+b]   = lvl;
    ST[(t+7)*128+b] = sn;
  }
}

// ---- gemm for layer 1: window_input built on the fly in staging ----
__global__ __launch_bounds__(256) void k_gemm1(
    const float* __restrict__ xT, const float* __restrict__ ST,
    const float* __restrict__ lvlT, const float* __restrict__ cats,
    const float* __restrict__ mp,
    const float* __restrict__ WT,   // [49][1024] f32
    const float* __restrict__ bias, // [1024] f32
    float* __restrict__ Z){
  __shared__ float Xs[8][52];
  const int tid = threadIdx.x;
  const int m0 = blockIdx.x*8;
  for(int idx=tid; idx<8*49; idx+=256){
    int p = idx/49, f = idx - p*49;
    int m = m0+p;
    float v = 0.f;
    if(m < NM){
      int tt = m/10, jj = m - (m/10)*10;
      if(f < 28){
        int c = tt + f;
        v = xT[c*128 + jj] / ST[c*128 + jj] / lvlT[(tt+27)*128 + jj];
      } else if(f < 48){
        v = cats[jj*20 + (f-28)];
      } else {
        v = mp[0];
      }
    }
    Xs[p][f] = v;
  }
  __syncthreads();
  float acc0[8], acc1[8], acc2[8], acc3[8];
  {
    float b0 = bias[tid];
    float b1 = bias[tid+256];
    float b2 = bias[tid+512];
    float b3 = bias[tid+768];
    #pragma unroll
    for(int p=0;p<8;p++){ acc0[p]=b0; acc1[p]=b1; acc2[p]=b2; acc3[p]=b3; }
  }
  #pragma unroll 7
  for(int f=0; f<49; f++){
    float w0 = WT[f*1024 + tid      ];
    float w1 = WT[f*1024 + tid+256  ];
    float w2 = WT[f*1024 + tid+512  ];
    float w3 = WT[f*1024 + tid+768  ];
    #pragma unroll
    for(int p=0;p<8;p++){
      float xv = Xs[p][f];
      acc0[p] += w0*xv; acc1[p] += w1*xv; acc2[p] += w2*xv; acc3[p] += w3*xv;
    }
  }
  for(int p=0;p<8;p++){
    int m = m0+p;
    if(m < NM){
      float* zb = Z + m*1024 + tid;
      zb[0]=acc0[p]; zb[256]=acc1[p]; zb[512]=acc2[p]; zb[768]=acc3[p];
    }
  }
}

// ---- batched xz = X @ WihT + b (F=256 layers) ----
__global__ __launch_bounds__(256) void k_gemm(const float* __restrict__ X,
                                              const float* __restrict__ WT,   // [256][1024] f32
                                              const float* __restrict__ bias, // [1024] f32
                                              float* __restrict__ Z){
  __shared__ float Xs[8][256];
  const int tid = threadIdx.x;
  const int m0 = blockIdx.x*8;
  for(int p=0;p<8;p++){
    int m = m0+p;
    Xs[p][tid] = (m < NM) ? X[m*256+tid] : 0.0f;
  }
  __syncthreads();
  float acc0[8], acc1[8], acc2[8], acc3[8];
  {
    float b0 = bias[tid];
    float b1 = bias[tid+256];
    float b2 = bias[tid+512];
    float b3 = bias[tid+768];
    #pragma unroll
    for(int p=0;p<8;p++){ acc0[p]=b0; acc1[p]=b1; acc2[p]=b2; acc3[p]=b3; }
  }
  #pragma unroll 4
  for(int f=0; f<256; f++){
    float w0 = WT[f*1024 + tid      ];
    float w1 = WT[f*1024 + tid+256  ];
    float w2 = WT[f*1024 + tid+512  ];
    float w3 = WT[f*1024 + tid+768  ];
    #pragma unroll
    for(int p=0;p<8;p++){
      float xv = Xs[p][f];
      acc0[p] += w0*xv; acc1[p] += w1*xv; acc2[p] += w2*xv; acc3[p] += w3*xv;
    }
  }
  for(int p=0;p<8;p++){
    int m = m0+p;
    if(m < NM){
      float* zb = Z + m*1024 + tid;
      zb[0]=acc0[p]; zb[256]=acc1[p]; zb[512]=acc2[p]; zb[768]=acc3[p];
    }
  }
}

// ---- LSTM scan vB: R11 pattern at 1024 threads (4 waves/SIMD for
// latency hiding). Thread (kg=tid&127, js=tid>>7 in 0..7): k-slice
// js*32..+32, rows {kg,kg+128,...}. 16 uint4 loads + 64 dot4/thread.
// NC of 16 combos in dynamic LDS, rest streamed from L2.
template<int NC>
__global__ __launch_bounds__(1024) void k_scanB(
    const float* __restrict__ Z,
    const u32* __restrict__ W8,    // packed int8 weights (256 KB)
    const float* __restrict__ zsc, // [1024] per-row z scales
    float* __restrict__ Y,
    const float* __restrict__ RES,
    int d){
  extern __shared__ u32 wl[];            // NC*4096 u32 cached weights
  __shared__ __align__(16) u32 h8[64];   // 256 int8 h
  __shared__ int   zp[8][1024];          // 32 KB partials
  __shared__ float sc[1024];             // 4 KB row scales
  const int tid = threadIdx.x;
  const int chain = blockIdx.x;
  const int j = chain % 10;
  const int r = chain / 10;
  const int ns = (273 - r + d - 1)/d;
  const int kg = tid & 127;
  const int js = tid >> 7;
  const uint4* Wg = (const uint4*)W8 + tid;      // combo stride 1024
  const uint4* hq = (const uint4*)h8 + js*2;     // 2 uint4 per js-slice
  uint4* wl4 = (uint4*)wl;

  if(tid < 1024) sc[tid] = zsc[tid];
  #pragma unroll
  for(int c=0;c<NC;c++)
    wl4[c*1024 + tid] = Wg[c*1024];
  if(tid < 64) h8[tid] = 0u;
  float cst = 0.0f;
  __syncthreads();

  int t = r;
  for(int s=0; s<ns; s++, t+=d){
    const size_t row = (size_t)(t*10 + j);
    float zv0=0.f, zv1=0.f, zv2=0.f, zv3=0.f, rv=0.f;
    if(tid < 256){                       // prefetch (consumed after barrier)
      const float* zb = Z + row*1024;
      zv0 = zb[tid]; zv1 = zb[tid+256]; zv2 = zb[tid+512]; zv3 = zb[tid+768];
      if(RES) rv = RES[row*256 + tid];
    }
    uint4 hh0 = hq[0], hh1 = hq[1];      // broadcast within wave
    int a0=0,a1=0,a2=0,a3=0,a4=0,a5=0,a6=0,a7=0;
    // streamed combos first (early global issue), then cached
    #pragma unroll
    for(int ci=0; ci<16; ci++){
      const int c = (ci + NC) & 15;
      const int rr = c & 7;
      uint4 w = (c < NC) ? wl4[c*1024 + tid] : Wg[c*1024];
      uint4 h4 = (c < 8) ? hh0 : hh1;    // q = c>>3
      int* ap = (rr==0)?&a0:(rr==1)?&a1:(rr==2)?&a2:(rr==3)?&a3:
                (rr==4)?&a4:(rr==5)?&a5:(rr==6)?&a6:&a7;
      int acc = *ap;
      acc = dot4(w.x, h4.x, acc);
      acc = dot4(w.y, h4.y, acc);
      acc = dot4(w.z, h4.z, acc);
      acc = dot4(w.w, h4.w, acc);
      *ap = acc;
    }
    zp[js][       kg] = a0;
    zp[js][128  + kg] = a1;
    zp[js][256  + kg] = a2;
    zp[js][384  + kg] = a3;
    zp[js][512  + kg] = a4;
    zp[js][640  + kg] = a5;
    zp[js][768  + kg] = a6;
    zp[js][896  + kg] = a7;
    __syncthreads();
    if(tid < 256){
      const int u = tid;
      int si=0, sf=0, sg=0, so=0;
      #pragma unroll
      for(int p=0;p<8;p++){
        si += zp[p][u];
        sf += zp[p][u+256];
        sg += zp[p][u+512];
        so += zp[p][u+768];
      }
      float zi = zv0 + sc[u]     * (float)si;
      float zf = zv1 + sc[u+256] * (float)sf;
      float zg = zv2 + sc[u+512] * (float)sg;
      float zo = zv3 + sc[u+768] * (float)so;
      float c  = sigf(zf)*cst + sigf(zi)*tanh_(zg);
      float h  = sigf(zo)*tanh_(c);
      cst = c;
      int hqi = __float2int_rn(h * 127.0f);
      hqi = max(-127, min(127, hqi));
      ((signed char*)h8)[u] = (signed char)hqi;
      Y[row*256 + u] = h + rv;
    }
    __syncthreads();
  }
}

// ---- fused head + all remaining outputs ----
__global__ __launch_bounds__(256) void k_headout(const float* __restrict__ Y4,
    const float* __restrict__ LWT,  // [256][256] f32 (linWT [f][u])
    const float* __restrict__ lb,
    const float* __restrict__ SWT,  // [256][28] f32  (scoreT [f][o])
    const float* __restrict__ sb,
    const float* __restrict__ ST, const float* __restrict__ lvlT,
    const float* __restrict__ xT, const float* __restrict__ val,
    float* __restrict__ out){
  __shared__ float v [8][256];
  __shared__ float h2[8][256];
  const int tid = threadIdx.x;
  if(blockIdx.x >= 342){
    int i = (blockIdx.x - 342)*256 + tid;
    if(i < N_O0){                        // actual_values
      int o = i % 28;
      int b = (i/28) % 128;
      int t = i/(28*128);
      int c = 28 + t + o;
      out[878080 + i] = xT[c*128+b] / ST[c*128+b] / lvlT[(27+t)*128+b];
    } else {
      i -= N_O0;
      if(i < 3584){                      // hav + hav_norm
        int b = i/28, o = i%28;
        int col = (o < 21) ? (286+o) : (279+o);
        float Sm = ST[col*128 + b];
        float lv = lvlT[299*128 + b];
        out[2738176 + i] = val[i];
        out[2741760 + i] = val[i] / Sm / lv;
      }
    }
    return;
  }
  const int m0 = blockIdx.x*8;
  for(int p=0;p<8;p++){
    int m = m0+p;
    v[p][tid] = (m<NM) ? Y4[m*256+tid] : 0.0f;
  }
  __syncthreads();
  float acc[8];
  float bz = lb[tid];
  #pragma unroll
  for(int p=0;p<8;p++) acc[p]=bz;
  #pragma unroll 4
  for(int f=0; f<256; f++){
    float w = LWT[f*256+tid];
    #pragma unroll
    for(int p=0;p<8;p++) acc[p] += w * v[p][f];
  }
  #pragma unroll
  for(int p=0;p<8;p++) h2[p][tid] = tanh_(acc[p]);
  __syncthreads();
  if(tid < 224){
    int o = tid % 28, p = tid / 28;
    int m = m0 + p;
    if(m < NM){
      float a = sb[o];
      for(int f=0; f<256; f++) a += SWT[f*28+o] * h2[p][f];
      int t = m / 10, j = m - t*10;
      float* o0 = out;                 // prediction_values (245,128,28)
      float* o3 = out + 1759744;       // rnn_out (273,128,28)
      for(int b=j; b<128; b+=10){
        size_t idx = (size_t)t*3584 + b*28 + o;
        o3[idx] = a;
        if(t < 245) o0[idx] = a;
      }
      if(t == 272){
        int col = (o < 21) ? (286+o) : (279+o);
        float* o2 = out + 1756160;     // holdout_prediction (128,28)
        for(int b=j; b<128; b+=10){
          float hv = a * ST[col*128 + b] * lvlT[299*128 + b];
          o2[b*28 + o] = (hv > 0.0f) ? hv : 0.0f;
        }
      }
    }
  }
}

extern "C" void kernel_launch(void* const* d_in, const int* in_sizes, int n_in,
                              void* d_out, int out_size, void* d_ws, size_t ws_size,
                              hipStream_t stream){
  (void)in_sizes; (void)n_in; (void)out_size; (void)ws_size;
  const float* x     = (const float*)d_in[0];
  const float* val   = (const float*)d_in[1];
  const float* alpha = (const float*)d_in[2];
  const float* gamma = (const float*)d_in[3];
  const float* iseas = (const float*)d_in[4];
  const float* cats  = (const float*)d_in[5];
  const float* mp    = (const float*)d_in[6];
  const float* Wih[4]  = {(const float*)d_in[7],  (const float*)d_in[10], (const float*)d_in[13], (const float*)d_in[16]};
  const float* Whh[4]  = {(const float*)d_in[8],  (const float*)d_in[11], (const float*)d_in[14], (const float*)d_in[17]};
  const float* bias[4] = {(const float*)d_in[9],  (const float*)d_in[12], (const float*)d_in[15], (const float*)d_in[18]};
  const float* linW  = (const float*)d_in[19];
  const float* linb  = (const float*)d_in[20];
  const float* scW   = (const float*)d_in[21];
  const float* scb   = (const float*)d_in[22];

  // ---- workspace layout ----
  float* Fw   = (float*)d_ws;
  float* ST   = Fw;                 // 39296
  float* lvlT = ST   + 39296;       // 38400
  float* xT   = lvlT + 38400;       // 38400
  float* xz   = xT   + 38400;       // 2795520
  float* yA   = xz   + 2795520;     // 698880  (L1 out / L3 out / L4 out)
  float* yB   = yA   + 698880;      // 698880  (L2 out, residual)
  float* wihT[4];
  wihT[0] = yB + 698880;            // 50176
  wihT[1] = wihT[0] + 50176;        // 262144
  wihT[2] = wihT[1] + 262144;
  wihT[3] = wihT[2] + 262144;
  float* linWT = wihT[3] + 262144;  // 65536
  float* scT   = linWT + 65536;     // 7168
  float* zsc   = scT   + 7168;      // 4096 (4 layers x 1024)
  u32*   W8all = (u32*)(zsc + 4096);// 4 x 65536 u32 = 1 MB

  // ---- dynamic-LDS budget for the big-cache scan variant ----
  const int smBig = 6*16384;        // 96 KB dynamic (+36.5 KB static)
  const int smSml = 1*16384;        // 16 KB dynamic (52.5 KB total)
  hipError_t ae = hipFuncSetAttribute((const void*)k_scanB<6>,
                    hipFuncAttributeMaxDynamicSharedMemorySize, smBig);
  const bool big = (ae == hipSuccess);

  // ---- prep: xT + transposes + row scales ----
  k_prep<<<3718, 256, 0, stream>>>(x, xT,
      Wih[0], wihT[0], Wih[1], wihT[1], Wih[2], wihT[2], Wih[3], wihT[3],
      linW, linWT, scW, scT,
      Whh[0], Whh[1], Whh[2], Whh[3], zsc);

  // ---- int8 pack + ES scan ----
  k_packes<<<1025, 256, 0, stream>>>(Whh[0], Whh[1], Whh[2], Whh[3], zsc, W8all,
                                     xT, alpha, gamma, iseas, ST, lvlT);

  // ---- 4 LSTM layers: Wih GEMM (win folded into L1) + int8 scan ----
  const int    dlt[4]    = {1, 2, 2, 6};
  const int    chains[4] = {10, 20, 20, 60};
  const float* Xin[4]    = {nullptr, yA, yB, yA};
  float*       Yout[4]   = {yA, yB, yA, yA};
  for(int l=0;l<4;l++){
    if(l == 0)
      k_gemm1<<<(NM+7)/8, 256, 0, stream>>>(xT, ST, lvlT, cats, mp,
                                            wihT[0], bias[0], xz);
    else
      k_gemm<<<(NM+7)/8, 256, 0, stream>>>(Xin[l], wihT[l], bias[l], xz);
    const float* res = (l==3) ? yB : (const float*)nullptr;
    if(big)
      k_scanB<6><<<chains[l], 1024, smBig, stream>>>(xz, W8all + l*65536,
                                        zsc + l*1024, Yout[l], res, dlt[l]);
    else
      k_scanB<1><<<chains[l], 1024, smSml, stream>>>(xz, W8all + l*65536,
                                        zsc + l*1024, Yout[l], res, dlt[l]);
  }

  // ---- fused head + outputs (+ actual_values + hav) ----
  k_headout<<<342 + (N_O0 + 3584 + 255)/256, 256, 0, stream>>>(
      yA, linWT, linb, scT, scb, ST, lvlT, xT, val, (float*)d_out);
}